// Round 2
// baseline (6567.208 us; speedup 1.0000x reference)
//
#include <hip/hip_runtime.h>
#include <hip/hip_bf16.h>
#include <cstdio>

typedef __hip_bfloat16 bf16;
using s8v   = __attribute__((ext_vector_type(8))) short;
using f32x4 = __attribute__((ext_vector_type(4))) float;

#define BB    256
#define NIMG  36
#define FDIM  2048
#define LSEQ  26
#define TSTEP 25
#define ADIM  512
#define EDIM  1024
#define DDIM  1024
#define VDIM  10000
#define VPAD  10112   /* 79*128 */
#define G4    4096
#define N3    4608    /* 4*D + A (q fused into ar-LSTM gemm) */
#define K1    5120    /* [h2|favg|e_t|h1] */
#define K2    4096    /* [aw|h1n|h2] */
#define K3    2048    /* [h1n|arh] */

__device__ inline float bf2f(bf16 x){ return __bfloat162float(x); }
__device__ inline bf16  f2bf(float x){ return __float2bfloat16(x); }
__device__ inline float sig_(float x){ return 1.0f/(1.0f + __expf(-x)); }
__device__ inline float tanh_(float x){ return tanhf(x); }

// ---------------------------------------------------------------------------
// NT GEMM: C(MxN,fp32) = A(MxK bf16 rowmajor) * Bw(NxK bf16 rowmajor)^T [+bias]
// split-K over blockIdx.z (partials at C + z*M*ldc). Optional A row remap.
// ---------------------------------------------------------------------------
template<int BM, int BN>
__global__ __launch_bounds__(256) void gemm_bt(
    const bf16* __restrict__ A, int lda,
    const bf16* __restrict__ Bw, int ldb,
    float* __restrict__ C, int ldc,
    int M, int Nreal, int Ktot, int nsplit,
    const float* __restrict__ bias,
    const int* __restrict__ rowmap)
{
  constexpr int BK = 32;
  constexpr int LW = 40;            // padded LDS row stride (elements)
  __shared__ bf16 sA[BM*LW];
  __shared__ bf16 sB[BN*LW];

  const int tid  = threadIdx.x;
  const int lane = tid & 63;
  const int wave = tid >> 6;
  const int wr = wave & 1, wc = wave >> 1;
  constexpr int TM = BM/32, TN = BN/32;

  const int bn = blockIdx.x, bm = blockIdx.y, bz = blockIdx.z;
  const int ks   = Ktot / nsplit;
  const int kbeg = bz * ks;

  const long arow0 = (long)bm*BM;
  const long bcol0 = (long)bn*BN;

  constexpr int AIT = (BM*4 + 255)/256;   // 16B chunks per thread for A tile
  constexpr int BIT = (BN*4 + 255)/256;
  const bf16* aptr[AIT]; bf16* asp[AIT];
  const bf16* bptr[BIT]; bf16* bsp[BIT]; bool bval[BIT];
#pragma unroll
  for (int u=0;u<AIT;u++){
    int c = tid + u*256; int r = c>>2, ch = c&3;
    long sr = arow0 + r;
    if (rowmap) sr = rowmap[sr];
    aptr[u] = A + sr*(long)lda + kbeg + ch*8;
    asp[u]  = &sA[r*LW + ch*8];
  }
#pragma unroll
  for (int u=0;u<BIT;u++){
    int c = tid + u*256; int r = c>>2, ch = c&3;
    long gc = bcol0 + r;
    bval[u] = (gc < (long)Nreal);
    bptr[u] = Bw + (bval[u] ? gc : 0)*(long)ldb + kbeg + ch*8;
    bsp[u]  = &sB[r*LW + ch*8];
  }

  f32x4 acc[TM][TN];
#pragma unroll
  for (int i=0;i<TM;i++)
#pragma unroll
    for (int j=0;j<TN;j++) acc[i][j] = (f32x4){0.f,0.f,0.f,0.f};

  const int m0 = lane & 15;
  const int q8 = (lane >> 4) * 8;

  for (int k0 = 0; k0 < ks; k0 += BK) {
#pragma unroll
    for (int u=0;u<AIT;u++)
      *(uint4*)asp[u] = *(const uint4*)(aptr[u] + k0);
#pragma unroll
    for (int u=0;u<BIT;u++){
      uint4 v = {0u,0u,0u,0u};
      if (bval[u]) v = *(const uint4*)(bptr[u] + k0);
      *(uint4*)bsp[u] = v;
    }
    __syncthreads();
    s8v afr[TM], bfr[TN];
#pragma unroll
    for (int i=0;i<TM;i++)
      afr[i] = *(const s8v*)&sA[(wr*(BM/2) + i*16 + m0)*LW + q8];
#pragma unroll
    for (int j=0;j<TN;j++)
      bfr[j] = *(const s8v*)&sB[(wc*(BN/2) + j*16 + m0)*LW + q8];
#pragma unroll
    for (int i=0;i<TM;i++)
#pragma unroll
      for (int j=0;j<TN;j++)
        acc[i][j] = __builtin_amdgcn_mfma_f32_16x16x32_bf16(afr[i], bfr[j], acc[i][j], 0, 0, 0);
    __syncthreads();
  }

  float* Cz = C + (long)bz * (long)M * (long)ldc;
  const int rq = lane >> 4;
#pragma unroll
  for (int i=0;i<TM;i++){
    long row = arow0 + wr*(BM/2) + i*16 + rq*4;
#pragma unroll
    for (int j=0;j<TN;j++){
      long col = bcol0 + wc*(BN/2) + j*16 + m0;
      float bv = 0.f;
      if (bias != nullptr && bz == 0 && col < (long)Nreal) bv = bias[col];
#pragma unroll
      for (int r=0;r<4;r++)
        Cz[(row + r)*(long)ldc + col] = acc[i][j][r] + bv;
    }
  }
}

// ---------------------------------------------------------------------------
// Setup kernels
// ---------------------------------------------------------------------------
__global__ __launch_bounds__(256) void sort_kernel(
    const int* __restrict__ sizesp, int* __restrict__ order,
    int* __restrict__ dec, float* __restrict__ bszf, int* __restrict__ rowmap)
{
  __shared__ int ssz[BB], so[BB], sd[BB];
  int b = threadIdx.x;
  ssz[b] = sizesp[b];
  __syncthreads();
  int s = ssz[b];
  int rank = 0;
  for (int j=0;j<BB;j++){
    int sj = ssz[j];
    rank += (sj > s) || (sj == s && j < b);
  }
  so[rank] = b;
  sd[rank] = s - 1;
  __syncthreads();
  order[b] = so[b];
  dec[b]   = sd[b];
  if (b < TSTEP){
    int c=0;
    for (int j=0;j<BB;j++) c += (sd[j] > b);
    bszf[b] = (float)(c > 0 ? c : 1);
  }
  for (int r=b; r<BB*NIMG; r+=BB) rowmap[r] = so[r/NIMG]*NIMG + (r%NIMG);
}

__global__ __launch_bounds__(256) void zero_f32(float* __restrict__ pz, long n){
  long i = (long)blockIdx.x*256 + threadIdx.x;
  if (i < n) pz[i] = 0.f;
}

// fp32 -> bf16 convert, 8 elements/thread (n must be a multiple of 8)
__global__ __launch_bounds__(256) void f2b_kernel(
    const float* __restrict__ s, bf16* __restrict__ d, long n)
{
  long i = ((long)blockIdx.x*256 + threadIdx.x)*8;
  if (i >= n) return;
  float4 a = *(const float4*)(s+i);
  float4 b = *(const float4*)(s+i+4);
  bf16 t[8] = {f2bf(a.x),f2bf(a.y),f2bf(a.z),f2bf(a.w),
               f2bf(b.x),f2bf(b.y),f2bf(b.z),f2bf(b.w)};
  *(uint4*)(d+i) = *(uint4*)t;
}

__global__ __launch_bounds__(256) void init_xcat(
    bf16* __restrict__ x1, bf16* __restrict__ x2, bf16* __restrict__ x3)
{
  int idx = blockIdx.x*256 + threadIdx.x;   // b*D + d
  int b = idx >> 10, d = idx & 1023;
  bf16 z = f2bf(0.f);
  x1[(long)b*K1 + d]        = z;   // h2 carry slot
  x1[(long)b*K1 + 4096 + d] = z;   // h1 carry slot
  x2[(long)b*K2 + 3072 + d] = z;   // h2 carry slot
  x3[(long)b*K3 + 1024 + d] = z;   // arh carry slot
}

__global__ __launch_bounds__(256) void favg_kernel(
    const float* __restrict__ feats, const int* __restrict__ order,
    bf16* __restrict__ x1)
{
  int idx = blockIdx.x*256 + threadIdx.x;   // b*F + f
  int b = idx >> 11, f = idx & 2047;
  const float* fb = feats + (long)order[b]*NIMG*FDIM + f;
  float s = 0.f;
#pragma unroll 4
  for (int n=0;n<NIMG;n++) s += fb[n*FDIM];
  x1[(long)b*K1 + 1024 + f] = f2bf(s * (1.0f/36.0f));
}

// concat fp32 sources [rows x k1 | rows x k2] -> bf16 dst, 8 elems/thread
__global__ __launch_bounds__(256) void concat2_f(
    bf16* __restrict__ dst, const float* __restrict__ s1, int k1,
    const float* __restrict__ s2, int k2, int rows)
{
  long nch = (long)rows*(k1+k2)/8;
  long c = (long)blockIdx.x*256 + threadIdx.x;
  if (c >= nch) return;
  long e = c*8;
  int ld = k1+k2;
  long r = e / ld; int col = (int)(e % ld);
  const float* src = (col < k1) ? (s1 + r*(long)k1 + col) : (s2 + r*(long)k2 + (col - k1));
  float4 a = *(const float4*)src;
  float4 b = *(const float4*)(src+4);
  bf16 t[8] = {f2bf(a.x),f2bf(a.y),f2bf(a.z),f2bf(a.w),
               f2bf(b.x),f2bf(b.y),f2bf(b.z),f2bf(b.w)};
  *(uint4*)(dst + e) = *(uint4*)t;
}

__global__ __launch_bounds__(256) void w3_attd_f(
    bf16* __restrict__ w3, const float* __restrict__ attd_w)
{
  long c = (long)blockIdx.x*256 + threadIdx.x;   // 512*2048/8 chunks
  long e = c*8;
  long r = e / 2048; int col = (int)(e % 2048);
  bf16 t[8];
  if (col < 1024){
    const float* src = attd_w + r*1024 + col;
    float4 a = *(const float4*)src;
    float4 b = *(const float4*)(src+4);
    t[0]=f2bf(a.x); t[1]=f2bf(a.y); t[2]=f2bf(a.z); t[3]=f2bf(a.w);
    t[4]=f2bf(b.x); t[5]=f2bf(b.y); t[6]=f2bf(b.z); t[7]=f2bf(b.w);
  } else {
    bf16 z = f2bf(0.f);
#pragma unroll
    for (int u=0;u<8;u++) t[u]=z;
  }
  *(uint4*)(w3 + (4096 + r)*2048 + col) = *(uint4*)t;
}

// ---------------------------------------------------------------------------
// Per-step kernels
// ---------------------------------------------------------------------------
__global__ __launch_bounds__(256) void embed_kernel(
    const int* __restrict__ seqs, const int* __restrict__ order,
    const float* __restrict__ emb, int t, bf16* __restrict__ x1)
{
  int idx = blockIdx.x*256 + threadIdx.x;   // b*E + e
  int b = idx >> 10, e = idx & 1023;
  int tok = seqs[order[b]*LSEQ + t];
  x1[(long)b*K1 + 3072 + e] = f2bf(emb[(long)tok*EDIM + e]);
}

__global__ __launch_bounds__(256) void gates1_kernel(
    const float* __restrict__ g, const float* __restrict__ bias,
    const float* __restrict__ h_old, float* __restrict__ h_new,
    float* __restrict__ c, const int* __restrict__ dec, int t,
    bf16* __restrict__ x1, bf16* __restrict__ x2, bf16* __restrict__ x3)
{
  int idx = blockIdx.x*256 + threadIdx.x;
  int b = idx >> 10, d = idx & 1023;
  float gi=0,gf=0,gg=0,go=0;
#pragma unroll
  for (int z=0; z<4; z++){
    const float* gz = g + (long)z*BB*G4 + (long)b*G4;
    gi += gz[d]; gf += gz[d+1024]; gg += gz[d+2048]; go += gz[d+3072];
  }
  gi += bias[d]; gf += bias[d+1024]; gg += bias[d+2048]; go += bias[d+3072];
  float cold = c[idx];
  float cn = sig_(gf)*cold + sig_(gi)*tanh_(gg);
  float hn = sig_(go)*tanh_(cn);
  bool act = t < dec[b];
  float hc = act ? hn : h_old[idx];
  float cc = act ? cn : cold;
  h_new[idx] = hc;
  c[idx] = cc;
  x1[(long)b*K1 + 4096 + d] = f2bf(hc);   // h1 carry for next-step td GEMM
  x2[(long)b*K2 + 2048 + d] = f2bf(hn);   // h1n (unmasked) into lang GEMM
  x3[(long)b*K3 + d]        = f2bf(hn);   // h1n (unmasked) into ar/q GEMM
}

__global__ __launch_bounds__(256) void gates2_kernel(
    const float* __restrict__ g, const float* __restrict__ bias,
    float* __restrict__ h2s, float* __restrict__ c2s,
    const int* __restrict__ dec, int t,
    bf16* __restrict__ h2n_bf, bf16* __restrict__ x1, bf16* __restrict__ x2)
{
  int idx = blockIdx.x*256 + threadIdx.x;
  int b = idx >> 10, d = idx & 1023;
  float gi=0,gf=0,gg=0,go=0;
#pragma unroll
  for (int z=0; z<4; z++){
    const float* gz = g + (long)z*BB*G4 + (long)b*G4;
    gi += gz[d]; gf += gz[d+1024]; gg += gz[d+2048]; go += gz[d+3072];
  }
  gi += bias[d]; gf += bias[d+1024]; gg += bias[d+2048]; go += bias[d+3072];
  float cold = c2s[idx];
  float cn = sig_(gf)*cold + sig_(gi)*tanh_(gg);
  float hn = sig_(go)*tanh_(cn);
  bool act = t < dec[b];
  float hc = act ? hn : h2s[idx];
  float cc = act ? cn : cold;
  h2s[idx] = hc;
  c2s[idx] = cc;
  h2n_bf[idx] = f2bf(hn);                 // unmasked -> vocab GEMM
  x1[(long)b*K1 + d]        = f2bf(hc);   // h2 carry for next-step td GEMM
  x2[(long)b*K2 + 3072 + d] = f2bf(hc);   // h2 carry for next-step lang GEMM
}

__global__ __launch_bounds__(256) void gates3_kernel(
    const float* __restrict__ g, const float* __restrict__ bias,
    float* __restrict__ arh, float* __restrict__ arc,
    const int* __restrict__ dec, int t,
    bf16* __restrict__ arhn_bf, bf16* __restrict__ x3)
{
  int idx = blockIdx.x*256 + threadIdx.x;
  int b = idx >> 10, d = idx & 1023;
  float gi=0,gf=0,gg=0,go=0;
#pragma unroll
  for (int z=0; z<2; z++){
    const float* gz = g + (long)z*BB*N3 + (long)b*N3;
    gi += gz[d]; gf += gz[d+1024]; gg += gz[d+2048]; go += gz[d+3072];
  }
  gi += bias[d]; gf += bias[d+1024]; gg += bias[d+2048]; go += bias[d+3072];
  float cold = arc[idx];
  float cn = sig_(gf)*cold + sig_(gi)*tanh_(gg);
  float hn = sig_(go)*tanh_(cn);
  bool act = t < dec[b];
  float hold = arh[idx];
  arh[idx] = act ? hn : hold;
  arc[idx] = act ? cn : cold;
  arhn_bf[idx] = f2bf(hn);                        // unmasked -> arl GEMM
  x3[(long)b*K3 + 1024 + d] = f2bf(act ? hn : hold);  // carry for next step
}

__global__ __launch_bounds__(256) void scores_kernel(
    const float* __restrict__ g3,          // q at cols [4096,4608), 2 split-K partials
    const float* __restrict__ imgatt,      // (B*NIMG) x A fp32 (no bias)
    const float* __restrict__ attf_b, const float* __restrict__ attd_b,
    const float* __restrict__ att_w, const float* __restrict__ att_b,
    float* __restrict__ scores)
{
  int gw = blockIdx.x*4 + (threadIdx.x >> 6);
  if (gw >= BB*NIMG) return;
  int lane = threadIdx.x & 63;
  int b = gw / NIMG;
  const float* q0 = g3 + (long)b*N3 + 4096;
  const float* q1 = g3 + (long)BB*N3 + (long)b*N3 + 4096;
  const float* ia = imgatt + (long)gw*ADIM;
  float s = 0.f;
#pragma unroll
  for (int u=0; u<8; u++){
    int a = u*64 + lane;
    float v = q0[a] + q1[a] + ia[a] + attf_b[a] + attd_b[a];
    v = fmaxf(v, 0.f);
    s += v * att_w[a];
  }
  for (int off=32; off; off>>=1) s += __shfl_down(s, off);
  if (lane == 0) scores[gw] = s + att_b[0];
}

__global__ __launch_bounds__(256) void attn_kernel(
    const float* __restrict__ scores, const bf16* __restrict__ feats_bf,
    const int* __restrict__ order, bf16* __restrict__ x2)
{
  int b = blockIdx.x;
  __shared__ float alpha[NIMG];
  int tid = threadIdx.x;
  if (tid < 64) {
    float v = (tid < NIMG) ? scores[b*NIMG + tid] : -1e30f;
    float m = v;
    for (int off=32; off; off>>=1) m = fmaxf(m, __shfl_down(m, off));
    m = __shfl(m, 0);
    float e = (tid < NIMG) ? __expf(v - m) : 0.f;
    float sum = e;
    for (int off=32; off; off>>=1) sum += __shfl_down(sum, off);
    sum = __shfl(sum, 0);
    if (tid < NIMG) alpha[tid] = e / sum;
  }
  __syncthreads();
  const bf16* fsb = feats_bf + (long)order[b]*NIMG*FDIM;
  for (int f = tid; f < FDIM; f += 256) {
    float s = 0.f;
#pragma unroll 4
    for (int n=0; n<NIMG; n++)
      s += alpha[n] * bf2f(fsb[n*FDIM + f]);
    x2[(long)b*K2 + f] = f2bf(s);
  }
}

__global__ __launch_bounds__(256) void loss_kernel(
    const float* __restrict__ arl_out,   // bias included (GEMM epilogue)
    const float* __restrict__ h_old,     // prev_h1 == h1 carry entering this step
    const int* __restrict__ dec, const float* __restrict__ bszf,
    int t, float* __restrict__ loss)
{
  if (t == 0) return;
  int b = blockIdx.x;
  float s = 0.f;
  for (int d = threadIdx.x; d < DDIM; d += 256) {
    float v = arl_out[(long)b*DDIM + d] - h_old[(long)b*DDIM + d];
    s += v*v;
  }
  __shared__ float red[4];
  for (int off=32; off; off>>=1) s += __shfl_down(s, off);
  if ((threadIdx.x & 63) == 0) red[threadIdx.x >> 6] = s;
  __syncthreads();
  if (threadIdx.x == 0 && (t < dec[b])) {
    float tot = red[0]+red[1]+red[2]+red[3];
    atomicAdd(loss, tot * (0.005f / bszf[t]));
  }
}

__global__ __launch_bounds__(256) void predout_kernel(
    const float* __restrict__ pred, const int* __restrict__ dec,
    int t, float* __restrict__ out)
{
  int idx = blockIdx.x*256 + threadIdx.x;   // b*V + v
  int b = idx / VDIM, v = idx % VDIM;
  bool act = t < dec[b];
  float p = act ? pred[(long)b*VPAD + v] : 0.f;
  out[((long)b*TSTEP + t)*VDIM + v] = p;
}

__global__ void finalize_kernel(const float* __restrict__ loss, float* __restrict__ out){
  if (threadIdx.x == 0) out[(long)BB*TSTEP*VDIM] = *loss;
}

// ---------------------------------------------------------------------------
extern "C" void kernel_launch(void* const* d_in, const int* in_sizes, int n_in,
                              void* d_out, int out_size, void* d_ws, size_t ws_size,
                              hipStream_t stream) {
  const float* feats    = (const float*)d_in[0];
  const int*   seqs     = (const int*)d_in[1];
  const int*   sizesp   = (const int*)d_in[2];
  const float* emb      = (const float*)d_in[3];
  const float* td_wih   = (const float*)d_in[4];
  const float* td_whh   = (const float*)d_in[5];
  const float* td_b     = (const float*)d_in[6];
  const float* lang_wih = (const float*)d_in[7];
  const float* lang_whh = (const float*)d_in[8];
  const float* lang_b   = (const float*)d_in[9];
  const float* attf_w   = (const float*)d_in[10];
  const float* attf_b   = (const float*)d_in[11];
  const float* attd_w   = (const float*)d_in[12];
  const float* attd_b   = (const float*)d_in[13];
  const float* att_w    = (const float*)d_in[14];
  const float* att_b    = (const float*)d_in[15];
  const float* out_w    = (const float*)d_in[16];
  const float* out_b    = (const float*)d_in[17];
  const float* ar_wih   = (const float*)d_in[18];
  const float* ar_whh   = (const float*)d_in[19];
  const float* ar_b     = (const float*)d_in[20];
  const float* arl_w    = (const float*)d_in[21];
  const float* arl_b    = (const float*)d_in[22];
  float* out = (float*)d_out;

  char* p = (char*)d_ws;
  auto alloc = [&](size_t n) -> void* {
    void* r = (void*)p; p += ((n + 255) & ~(size_t)255); return r;
  };
  const long SD = (long)BB*DDIM;   // 262144 floats per state

  int*   order    = (int*)  alloc(BB*4);
  int*   dec      = (int*)  alloc(BB*4);
  float* bszf     = (float*)alloc(TSTEP*4);
  int*   rowmap   = (int*)  alloc(BB*NIMG*4);
  float* stateblk = (float*)alloc((7*SD + 64)*4);  // h1A,h1B,c1,h2,c2,arh,arc,loss
  bf16*  W1       = (bf16*) alloc((size_t)G4*K1*2);
  bf16*  W2       = (bf16*) alloc((size_t)G4*K2*2);
  bf16*  W3       = (bf16*) alloc((size_t)N3*K3*2);
  bf16*  feats_bf = (bf16*) alloc((size_t)BB*NIMG*FDIM*2);
  bf16*  attf_bf  = (bf16*) alloc((size_t)ADIM*FDIM*2);
  bf16*  outw_bf  = (bf16*) alloc((size_t)VDIM*DDIM*2);
  bf16*  arlw_bf  = (bf16*) alloc((size_t)DDIM*DDIM*2);
  bf16*  xcat1    = (bf16*) alloc((size_t)BB*K1*2);
  bf16*  xcat2    = (bf16*) alloc((size_t)BB*K2*2);
  bf16*  xcat3    = (bf16*) alloc((size_t)BB*K3*2);
  bf16*  h2n_bf   = (bf16*) alloc((size_t)BB*DDIM*2);
  bf16*  arhn_bf  = (bf16*) alloc((size_t)BB*DDIM*2);
  float* g12      = (float*)alloc((size_t)4*BB*G4*4);   // 4 split-K partials
  float* g3       = (float*)alloc((size_t)2*BB*N3*4);   // 2 split-K partials
  float* imgatt   = (float*)alloc((size_t)BB*NIMG*ADIM*4);
  float* scorebuf = (float*)alloc((size_t)BB*NIMG*4);
  float* arl_out  = (float*)alloc((size_t)BB*DDIM*4);
  float* predbuf  = g12;   // alias: temporally disjoint from g12 within a step

  size_t need = (size_t)(p - (char*)d_ws);
  if (need > ws_size) {
    fprintf(stderr, "kernel_launch: ws too small: need %zu have %zu\n", need, ws_size);
    return;
  }

  float* h1A = stateblk;
  float* h1B = stateblk + SD;
  float* c1  = stateblk + 2*SD;
  float* h2s = stateblk + 3*SD;
  float* c2s = stateblk + 4*SD;
  float* arh = stateblk + 5*SD;
  float* arc = stateblk + 6*SD;
  float* loss = stateblk + 7*SD;

  // ---- setup ----
  sort_kernel<<<1, 256, 0, stream>>>(sizesp, order, dec, bszf, rowmap);
  long nz = 7*SD + 64;
  zero_f32<<<(int)((nz + 255)/256), 256, 0, stream>>>(stateblk, nz);
  init_xcat<<<1024, 256, 0, stream>>>(xcat1, xcat2, xcat3);
  favg_kernel<<<2048, 256, 0, stream>>>(feats, order, xcat1);
  f2b_kernel<<<9216, 256, 0, stream>>>(feats,  feats_bf, (long)BB*NIMG*FDIM);
  f2b_kernel<<< 512, 256, 0, stream>>>(attf_w, attf_bf,  (long)ADIM*FDIM);
  f2b_kernel<<<5000, 256, 0, stream>>>(out_w,  outw_bf,  (long)VDIM*DDIM);
  f2b_kernel<<< 512, 256, 0, stream>>>(arl_w,  arlw_bf,  (long)DDIM*DDIM);
  concat2_f<<<10240, 256, 0, stream>>>(W1, td_wih, 4096, td_whh, 1024, 4096);
  concat2_f<<< 8192, 256, 0, stream>>>(W2, lang_wih, 3072, lang_whh, 1024, 4096);
  concat2_f<<< 4096, 256, 0, stream>>>(W3, ar_wih, 1024, ar_whh, 1024, 4096);
  w3_attd_f<<<512, 256, 0, stream>>>(W3, attd_w);
  // img_att = fs @ attf_w^T  (fs via rowmap gather), no bias (added in scores)
  gemm_bt<128,128><<<dim3(4,72,1), 256, 0, stream>>>(
      feats_bf, FDIM, attf_bf, FDIM, imgatt, ADIM, BB*NIMG, ADIM, FDIM, 1, nullptr, rowmap);

  // ---- recurrence ----
  for (int t = 0; t < TSTEP; t++) {
    float* h1old = (t & 1) ? h1B : h1A;
    float* h1new = (t & 1) ? h1A : h1B;

    embed_kernel<<<1024, 256, 0, stream>>>(seqs, order, emb, t, xcat1);

    gemm_bt<128,128><<<dim3(32,2,4), 256, 0, stream>>>(   // td gates
        xcat1, K1, W1, K1, g12, G4, BB, G4, K1, 4, nullptr, nullptr);
    gates1_kernel<<<1024, 256, 0, stream>>>(
        g12, td_b, h1old, h1new, c1, dec, t, xcat1, xcat2, xcat3);

    gemm_bt<128,128><<<dim3(36,2,2), 256, 0, stream>>>(   // ar gates + q (fused)
        xcat3, K3, W3, K3, g3, N3, BB, N3, K3, 2, nullptr, nullptr);
    gates3_kernel<<<1024, 256, 0, stream>>>(
        g3, ar_b, arh, arc, dec, t, arhn_bf, xcat3);

    scores_kernel<<<2304, 256, 0, stream>>>(
        g3, imgatt, attf_b, attd_b, att_w, att_b, scorebuf);
    attn_kernel<<<256, 256, 0, stream>>>(scorebuf, feats_bf, order, xcat2);

    gemm_bt<128,128><<<dim3(32,2,4), 256, 0, stream>>>(   // lang gates
        xcat2, K2, W2, K2, g12, G4, BB, G4, K2, 4, nullptr, nullptr);
    gates2_kernel<<<1024, 256, 0, stream>>>(
        g12, lang_b, h2s, c2s, dec, t, h2n_bf, xcat1, xcat2);

    gemm_bt<64,64><<<dim3(16,4,1), 256, 0, stream>>>(     // arl projection
        arhn_bf, DDIM, arlw_bf, DDIM, arl_out, DDIM, BB, DDIM, DDIM, 1, arl_b, nullptr);
    loss_kernel<<<256, 256, 0, stream>>>(arl_out, h1old, dec, bszf, t, loss);

    gemm_bt<128,128><<<dim3(79,2,1), 256, 0, stream>>>(   // vocab projection
        h2n_bf, DDIM, outw_bf, DDIM, predbuf, VPAD, BB, VDIM, DDIM, 1, out_b, nullptr);
    predout_kernel<<<10000, 256, 0, stream>>>(predbuf, dec, t, out);
  }

  finalize_kernel<<<1, 64, 0, stream>>>(loss, out);
}